// Round 1
// baseline (1280.606 us; speedup 1.0000x reference)
//
#include <hip/hip_runtime.h>

#define NV 128
#define ROWS 256     // rows per block == threads per block
#define CH 16        // column chunk staged through LDS
#define PAD 257      // LDS row pad (floats): stride 257 -> conflict-free lanes

// Pre-kernel: w_eff = tril(weight * mask). Makes the main kernel's weight
// accesses pure uniform loads of a single precomputed array (scalarizable),
// and folds the mask multiply out of the hot loop.
__global__ void prep_w(const float* __restrict__ weight,
                       const float* __restrict__ mask,
                       float* __restrict__ weff) {
    int idx = blockIdx.x * 256 + threadIdx.x;
    if (idx < NV * NV) {
        int r = idx >> 7;
        int c = idx & (NV - 1);
        float v = (c <= r) ? weight[idx] * mask[idx] : 0.0f;
        weff[idx] = v;
    }
}

// Main kernel: per-thread forward substitution, z kept entirely in VGPRs.
// x staged through LDS (transposed) for coalesced global reads; w read via
// wave-uniform scalar loads (SMEM pipe).
__global__ __launch_bounds__(256, 2) void sem_fs(const float* __restrict__ x,
                                                 const float* __restrict__ w,
                                                 float* __restrict__ out) {
    __shared__ float xs[2][CH][PAD];   // [buf][col-in-chunk][row] transposed
    const int tid = threadIdx.x;
    const long rowbase = (long)blockIdx.x * ROWS;

    float z[NV];
    float4 pf[4];

    const int cc = tid & 3;   // which float4 of the 16-col chunk
    const int r0 = tid >> 2;  // 0..63: base row this thread loads

    // ---- prologue: load chunk 0 and stage it ----
    {
#pragma unroll
        for (int q = 0; q < 4; ++q) {
            int r = q * 64 + r0;
            pf[q] = *reinterpret_cast<const float4*>(x + (rowbase + r) * NV + 0 * CH + cc * 4);
        }
#pragma unroll
        for (int q = 0; q < 4; ++q) {
            int r = q * 64 + r0;
            xs[0][cc * 4 + 0][r] = pf[q].x;
            xs[0][cc * 4 + 1][r] = pf[q].y;
            xs[0][cc * 4 + 2][r] = pf[q].z;
            xs[0][cc * 4 + 3][r] = pf[q].w;
        }
    }

#pragma unroll
    for (int c = 0; c < NV / CH; ++c) {
        // issue prefetch of chunk c+1 (latency hidden under compute below)
        if (c < NV / CH - 1) {
#pragma unroll
            for (int q = 0; q < 4; ++q) {
                int r = q * 64 + r0;
                pf[q] = *reinterpret_cast<const float4*>(x + (rowbase + r) * NV + (c + 1) * CH + cc * 4);
            }
        }
        __syncthreads();  // buf[c&1] staged & visible; prev reads of buf[(c+1)&1] done

        // ---- compute 16 substitution steps out of LDS buf[c&1] ----
#pragma unroll
        for (int ii = 0; ii < CH; ++ii) {
            const int i = c * CH + ii;
            const float xi = xs[c & 1][ii][tid];
            const float* wrow = w + i * NV;   // uniform -> scalar loads
            float a0 = wrow[i] * xi;
            float a1 = 0.0f, a2 = 0.0f, a3 = 0.0f;
            int j = 0;
#pragma unroll
            for (; j + 3 < i; j += 4) {
                a0 += wrow[j + 0] * z[j + 0];
                a1 += wrow[j + 1] * z[j + 1];
                a2 += wrow[j + 2] * z[j + 2];
                a3 += wrow[j + 3] * z[j + 3];
            }
#pragma unroll
            for (; j < i; ++j) a0 += wrow[j] * z[j];
            z[i] = (a0 + a1) + (a2 + a3);
        }

        // stage prefetched chunk c+1 into the other buffer
        if (c < NV / CH - 1) {
#pragma unroll
            for (int q = 0; q < 4; ++q) {
                int r = q * 64 + r0;
                xs[(c + 1) & 1][cc * 4 + 0][r] = pf[q].x;
                xs[(c + 1) & 1][cc * 4 + 1][r] = pf[q].y;
                xs[(c + 1) & 1][cc * 4 + 2][r] = pf[q].z;
                xs[(c + 1) & 1][cc * 4 + 3][r] = pf[q].w;
            }
        }
    }

    // ---- store the full row; 32 back-to-back float4 so L2 lines fill fast ----
    float* orow = out + (rowbase + tid) * NV;
#pragma unroll
    for (int k = 0; k < NV / 4; ++k) {
        *reinterpret_cast<float4*>(orow + 4 * k) =
            make_float4(z[4 * k + 0], z[4 * k + 1], z[4 * k + 2], z[4 * k + 3]);
    }
}

extern "C" void kernel_launch(void* const* d_in, const int* in_sizes, int n_in,
                              void* d_out, int out_size, void* d_ws, size_t ws_size,
                              hipStream_t stream) {
    const float* x      = (const float*)d_in[0];
    const float* weight = (const float*)d_in[1];
    const float* mask   = (const float*)d_in[2];
    float* out  = (float*)d_out;
    float* weff = (float*)d_ws;   // 64 KB scratch for tril(weight*mask)

    hipLaunchKernelGGL(prep_w, dim3((NV * NV + 255) / 256), dim3(256), 0, stream,
                       weight, mask, weff);

    const int batch = in_sizes[0] / NV;       // 524288
    const int grid  = batch / ROWS;           // 2048
    hipLaunchKernelGGL(sem_fs, dim3(grid), dim3(256), 0, stream, x, weff, out);
}

// Round 2
// 663.172 us; speedup vs baseline: 1.9310x; 1.9310x over previous
//
#include <hip/hip_runtime.h>

#define NV 128
#define ROWS 256     // rows per block == threads per block
#define CH 16        // column chunk staged through LDS
#define PAD 257      // LDS row stride in floats

// Pre-kernel: w_eff = tril(weight * mask), upper triangle zeroed.
// Zero-padding above the diagonal is what lets the main kernel run fixed
// 16-multiple k-loops (padded terms multiply a zeroed w or a still-zero z).
__global__ void prep_w(const float* __restrict__ weight,
                       const float* __restrict__ mask,
                       float* __restrict__ weff) {
    int idx = blockIdx.x * 256 + threadIdx.x;
    if (idx < NV * NV) {
        int r = idx >> 7;
        int c = idx & (NV - 1);
        float v = (c <= r) ? weight[idx] * mask[idx] : 0.0f;
        weff[idx] = v;
    }
}

// Issue global loads for column-chunk c (4 x float4 per thread, in flight
// until stage() consumes them).
__device__ __forceinline__ void prefetch(int c, float4 pf[4],
                                         const float* __restrict__ x,
                                         long rowbase, int r0, int cc) {
#pragma unroll
    for (int q = 0; q < 4; ++q) {
        int r = q * 64 + r0;
        pf[q] = *reinterpret_cast<const float4*>(x + (rowbase + r) * NV + c * CH + cc * 4);
    }
}

// Transpose-stage the prefetched chunk into LDS: xs[col][row].
__device__ __forceinline__ void stage(float* __restrict__ buf, const float4 pf[4],
                                      int cc, int r0) {
#pragma unroll
    for (int q = 0; q < 4; ++q) {
        int r = q * 64 + r0;
        buf[(cc * 4 + 0) * PAD + r] = pf[q].x;
        buf[(cc * 4 + 1) * PAD + r] = pf[q].y;
        buf[(cc * 4 + 2) * PAD + r] = pf[q].z;
        buf[(cc * 4 + 3) * PAD + r] = pf[q].w;
    }
}

// 16 substitution steps for column block C. ALL indices compile-time:
// C is a template arg, ii/k loops have literal bounds and fully unroll.
// k runs to the padded bound (C+1)*16: for k in (i, (C+1)*16) either
// w[i][k]==0 (upper triangle zeroed) or z[k]==0 (not yet computed), so
// padding adds exactly 0. w reads are wave-uniform -> scalar loads.
template <int C>
__device__ __forceinline__ void do_block(float z[NV], const float* __restrict__ w,
                                         const float* __restrict__ xsbuf, int tid) {
#pragma unroll
    for (int ii = 0; ii < CH; ++ii) {
        const int i = C * CH + ii;
        const float xi = xsbuf[ii * PAD + tid];
        const float* wrow = w + i * NV;
        float a0 = wrow[i] * xi;   // diagonal * x  (z[i] is still 0 below)
        float a1 = 0.0f, a2 = 0.0f, a3 = 0.0f;
#pragma unroll
        for (int k = 0; k < (C + 1) * CH; k += 4) {
            a0 = fmaf(wrow[k + 0], z[k + 0], a0);
            a1 = fmaf(wrow[k + 1], z[k + 1], a1);
            a2 = fmaf(wrow[k + 2], z[k + 2], a2);
            a3 = fmaf(wrow[k + 3], z[k + 3], a3);
        }
        z[i] = (a0 + a1) + (a2 + a3);
    }
}

__global__ __launch_bounds__(256, 2) void sem_fs(const float* __restrict__ x,
                                                 const float* __restrict__ w,
                                                 float* __restrict__ out) {
    __shared__ float xs[2][CH * PAD];
    const int tid = threadIdx.x;
    const long rowbase = (long)blockIdx.x * ROWS;
    const int cc = tid & 3;   // which float4 of the 16-col chunk
    const int r0 = tid >> 2;  // base row for staging loads

    float z[NV];
#pragma unroll
    for (int i = 0; i < NV; ++i) z[i] = 0.0f;

    float4 pf[4];
    prefetch(0, pf, x, rowbase, r0, cc);
    stage(xs[0], pf, cc, r0);

    // Per step: barrier (chunk c staged everywhere) -> issue loads for c+1
    // (latency hides under 16 rows of FMA) -> compute -> stage c+1.
    // Buffer safety: stage into xs[(c+1)&1] only happens after the barrier
    // that follows every wave's compute on that same buffer (c-1).
#define STEP(c)                                                 \
    __syncthreads();                                            \
    if ((c) < NV / CH - 1) prefetch((c) + 1, pf, x, rowbase, r0, cc); \
    do_block<(c)>(z, w, xs[(c) & 1], tid);                      \
    if ((c) < NV / CH - 1) stage(xs[((c) + 1) & 1], pf, cc, r0);

    STEP(0) STEP(1) STEP(2) STEP(3) STEP(4) STEP(5) STEP(6) STEP(7)
#undef STEP

    // Store the full row: 32 back-to-back float4; wave fills whole 128B
    // lines within a few instructions so L2 merges into full-line writebacks.
    float* orow = out + (rowbase + tid) * NV;
#pragma unroll
    for (int k = 0; k < NV / 4; ++k) {
        *reinterpret_cast<float4*>(orow + 4 * k) =
            make_float4(z[4 * k + 0], z[4 * k + 1], z[4 * k + 2], z[4 * k + 3]);
    }
}

extern "C" void kernel_launch(void* const* d_in, const int* in_sizes, int n_in,
                              void* d_out, int out_size, void* d_ws, size_t ws_size,
                              hipStream_t stream) {
    const float* x      = (const float*)d_in[0];
    const float* weight = (const float*)d_in[1];
    const float* mask   = (const float*)d_in[2];
    float* out  = (float*)d_out;
    float* weff = (float*)d_ws;   // 64 KB scratch for tril(weight*mask)

    hipLaunchKernelGGL(prep_w, dim3((NV * NV + 255) / 256), dim3(256), 0, stream,
                       weight, mask, weff);

    const int batch = in_sizes[0] / NV;       // 524288
    const int grid  = batch / ROWS;           // 2048
    hipLaunchKernelGGL(sem_fs, dim3(grid), dim3(256), 0, stream, x, weff, out);
}